// Round 13
// baseline (256.700 us; speedup 1.0000x reference)
//
#include <hip/hip_runtime.h>

typedef __attribute__((ext_vector_type(8))) short bf16x8;
typedef __attribute__((ext_vector_type(4))) float f32x4;
typedef __attribute__((ext_vector_type(16))) float f32x16;

#define MFMA16(a, b, c) __builtin_amdgcn_mfma_f32_16x16x32_bf16(a, b, c, 0, 0, 0)
#define MFMA32(a, b, c) __builtin_amdgcn_mfma_f32_32x32x16_bf16(a, b, c, 0, 0, 0)
#define LOG2E 1.4426950408889634f
#define MB2 46.16624868f   // 32 * log2(e): fixed softmax shift

// Problem constants
#define BB 2
#define TT 2048
#define CC 768
#define HH 12
#define DD 64
#define MM (BB * TT)      // 4096
#define N1 (3 * CC)       // 2304
#define BH_STRIDE 131072  // TT*DD shorts per bh

static __device__ __forceinline__ unsigned short f2bf(float f) {
  union { float f; unsigned u; } v; v.f = f;
  unsigned r = (v.u + 0x7FFFu + ((v.u >> 16) & 1u)) >> 16;
  return (unsigned short)r;
}

static __device__ __forceinline__ float bf2f(unsigned short s) {
  union { unsigned u; float f; } v; v.u = ((unsigned)s) << 16;
  return v.f;
}

static __device__ __forceinline__ unsigned cvt_pk_bf16(float lo, float hi) {
  unsigned r;
  asm("v_cvt_pk_bf16_f32 %0, %1, %2" : "=v"(r) : "v"(lo), "v"(hi));
  return r;
}

static __device__ __forceinline__ void gload_lds16(const void* g, void* l) {
  __builtin_amdgcn_global_load_lds(
      (const __attribute__((address_space(1))) void*)g,
      (__attribute__((address_space(3))) void*)l, 16, 0, 0);
}

// ---------- fused prep ----------
#define PREP_CVT 3072
#define PREP_TR1 1728
#define PREP_TR2 576
__global__ __launch_bounds__(256) void k_prep(
    const float* __restrict__ x, unsigned short* __restrict__ Xb,
    const float* __restrict__ Wa, unsigned short* __restrict__ WaT,
    const float* __restrict__ Wp, unsigned short* __restrict__ WpT,
    const int* __restrict__ mask, unsigned int* __restrict__ mb) {
  __shared__ float tile[32][33];
  const int bid = blockIdx.x;
  const int tid = threadIdx.x;
  if (bid < PREP_CVT) {
    const int i = bid * 256 + tid;
    float4 v = reinterpret_cast<const float4*>(x)[i];
    ushort4 r;
    r.x = f2bf(v.x); r.y = f2bf(v.y); r.z = f2bf(v.z); r.w = f2bf(v.w);
    reinterpret_cast<ushort4*>(Xb)[i] = r;
  } else if (bid < PREP_CVT + PREP_TR1 + PREP_TR2) {
    const bool first = bid < PREP_CVT + PREP_TR1;
    const int b = first ? bid - PREP_CVT : bid - PREP_CVT - PREP_TR1;
    const int nb = first ? 72 : 24;
    const int N = first ? N1 : CC;
    const float* W = first ? Wa : Wp;
    unsigned short* Wt = first ? WaT : WpT;
    const int n0 = (b % nb) * 32, k0 = (b / nb) * 32;
    const int tx = tid & 31, ty = tid >> 5;
#pragma unroll
    for (int i = 0; i < 4; ++i)
      tile[ty + i * 8][tx] = W[(size_t)(k0 + ty + i * 8) * N + n0 + tx];
    __syncthreads();
#pragma unroll
    for (int i = 0; i < 4; ++i)
      Wt[(size_t)(n0 + ty + i * 8) * CC + k0 + tx] = f2bf(tile[tx][ty + i * 8]);
  } else {
    if (tid < 128) {
      unsigned bits = 0;
      const int* p = mask + tid * 32;
#pragma unroll
      for (int j = 0; j < 32; ++j) bits |= (p[j] != 0 ? 1u : 0u) << j;
      mb[tid] = bits;
    }
  }
}

// ---------- bf16 GEMM: 128xBN tile, BK=32, 3-buffer counted-vmcnt pipeline ----------
template <int MODE, int BN>
__global__ __launch_bounds__(256) void k_gemm(
    const unsigned short* __restrict__ A, const unsigned short* __restrict__ Bt,
    const float* __restrict__ bias, float* __restrict__ Cout, int N, int K,
    unsigned short* __restrict__ Qb, unsigned short* __restrict__ Kb,
    unsigned short* __restrict__ Vt) {
  constexpr int NI = BN / 32;
  __shared__ __align__(16) unsigned short As[3][128 * 32];
  __shared__ __align__(16) unsigned short Bs[3][BN * 32];
  const int tid = threadIdx.x;
  const int lane = tid & 63;
  const int wid = tid >> 6;
  const int l15 = lane & 15, l4 = lane >> 4;
  const int wr = wid >> 1, wc = wid & 1;
  const int brow = blockIdx.x * 128, bcol = blockIdx.y * BN;

  f32x4 acc[4][NI] = {};

  const int srow = tid >> 2;
  const int usrc = (tid & 3) ^ ((tid >> 3) & 3);
  const unsigned short* gA0 = A + (size_t)(brow + srow) * K + usrc * 8;
  const unsigned short* gA1 = gA0 + (size_t)64 * K;
  const unsigned short* gB0 = Bt + (size_t)(bcol + srow) * K + usrc * 8;
  const unsigned short* gB1 = (BN == 128) ? gB0 + (size_t)64 * K : gB0;
  const int dslot = tid * 8;

  const int NT = K / 32;

#define STAGE(t, buf)                                       \
  do {                                                      \
    const int ko = (t) * 32;                                \
    gload_lds16(gA0 + ko, &As[buf][dslot]);                 \
    gload_lds16(gA1 + ko, &As[buf][dslot + 2048]);          \
    gload_lds16(gB0 + ko, &Bs[buf][dslot]);                 \
    if (BN == 128) gload_lds16(gB1 + ko, &Bs[buf][dslot + 2048]); \
  } while (0)

  const int swz = (l4 ^ ((l15 >> 1) & 3)) * 8;
  const int arow = wr * 64 + l15;
  const int brow2 = wc * (BN / 2) + l15;

  STAGE(0, 0);
  STAGE(1, 1);

  int cur = 0;
  for (int t = 0; t < NT - 1; ++t) {
    if (BN == 128) asm volatile("s_waitcnt vmcnt(4)" ::: "memory");
    else           asm volatile("s_waitcnt vmcnt(3)" ::: "memory");
    __builtin_amdgcn_s_barrier();
    if (t + 2 < NT) {
      int nb = cur + 2; if (nb >= 3) nb -= 3;
      STAGE(t + 2, nb);
    }
    bf16x8 af[4], bfr[NI];
#pragma unroll
    for (int mi = 0; mi < 4; ++mi)
      af[mi] = *reinterpret_cast<const bf16x8*>(&As[cur][(arow + mi * 16) * 32 + swz]);
#pragma unroll
    for (int ni = 0; ni < NI; ++ni)
      bfr[ni] = *reinterpret_cast<const bf16x8*>(&Bs[cur][(brow2 + ni * 16) * 32 + swz]);
#pragma unroll
    for (int mi = 0; mi < 4; ++mi)
#pragma unroll
      for (int ni = 0; ni < NI; ++ni)
        acc[mi][ni] = MFMA16(af[mi], bfr[ni], acc[mi][ni]);
    cur = (cur == 2) ? 0 : cur + 1;
  }
  asm volatile("s_waitcnt vmcnt(0)" ::: "memory");
  __builtin_amdgcn_s_barrier();
  {
    bf16x8 af[4], bfr[NI];
#pragma unroll
    for (int mi = 0; mi < 4; ++mi)
      af[mi] = *reinterpret_cast<const bf16x8*>(&As[cur][(arow + mi * 16) * 32 + swz]);
#pragma unroll
    for (int ni = 0; ni < NI; ++ni)
      bfr[ni] = *reinterpret_cast<const bf16x8*>(&Bs[cur][(brow2 + ni * 16) * 32 + swz]);
#pragma unroll
    for (int mi = 0; mi < 4; ++mi)
#pragma unroll
      for (int ni = 0; ni < NI; ++ni)
        acc[mi][ni] = MFMA16(af[mi], bfr[ni], acc[mi][ni]);
  }
#undef STAGE

#pragma unroll
  for (int mi = 0; mi < 4; ++mi) {
    const int m0 = brow + wr * 64 + mi * 16 + l4 * 4;
#pragma unroll
    for (int ni = 0; ni < NI; ++ni) {
      const int n = bcol + wc * (BN / 2) + ni * 16 + l15;
      const float bv = bias[n];
      if (MODE == 0) {
#pragma unroll
        for (int r = 0; r < 4; ++r)
          Cout[(size_t)(m0 + r) * N + n] = acc[mi][ni][r] + bv;
      } else {
        const int sec = n / CC;
        const int nn = n - sec * CC;
        const int hh = nn >> 6, d = nn & 63;
        const int b = m0 >> 11;
        const int t0 = m0 & 2047;
        const size_t hbase = (size_t)(b * HH + hh) * BH_STRIDE;
        if (sec == 0) {
#pragma unroll
          for (int r = 0; r < 4; ++r) {
            const int t = t0 + r;
            Qb[hbase + ((t >> 5) * 4 + (d >> 4)) * 512 + (t & 31) * 16 + (d & 15)] =
                f2bf((acc[mi][ni][r] + bv) * 0.125f);
          }
        } else if (sec == 1) {
#pragma unroll
          for (int r = 0; r < 4; ++r) {
            const int t = t0 + r;
            Kb[hbase + ((t >> 5) * 4 + (d >> 4)) * 512 + (t & 31) * 16 + (d & 15)] =
                f2bf(acc[mi][ni][r] + bv);
          }
        } else {
          ushort4 pk;
          pk.x = f2bf(acc[mi][ni][0] + bv);
          pk.y = f2bf(acc[mi][ni][1] + bv);
          pk.z = f2bf(acc[mi][ni][2] + bv);
          pk.w = f2bf(acc[mi][ni][3] + bv);
          *reinterpret_cast<ushort4*>(
              &Vt[hbase + ((t0 >> 6) * 4 + ((t0 >> 4) & 3)) * 1024 + d * 16 + (t0 & 15)]) = pk;
        }
      }
    }
  }
}

// ---------- causal flash attention, phase 1 ----------
// 64-row waves: wave owns q-blocks (2k, 2k+1) which have IDENTICAL nt = k+1
// -> each K/V tile load serves 64 q-rows (zero wasted MFMA).
// Block = 4 waves = row-groups {4G..4G+3} sharing a KV chunk (L1 reuse).
__device__ __forceinline__ void loadk(bf16x8 (&dst)[2][4], const unsigned short* Kh,
                                      int kv0, int lo) {
  const unsigned short* kp = Kh + (kv0 >> 5) * 2048 + lo;
#pragma unroll
  for (int kg = 0; kg < 2; ++kg)
#pragma unroll
    for (int dg = 0; dg < 4; ++dg)
      dst[kg][dg] = *reinterpret_cast<const bf16x8*>(&kp[kg * 2048 + dg * 512]);
}

// softmax + bf16 pack for one 32-row q-block (scores s0: keys kv0.., s1: kv0+32..)
__device__ __forceinline__ void softmax_pack(
    f32x16& s0, f32x16& s1, uint2 mb, int kv0, int q0x, int l31, int h,
    float& lrow, unsigned (&pk0)[4][2], unsigned (&pk1)[4][2]) {
  if ((mb.x & mb.y) != 0xffffffffu) {
#pragma unroll
    for (int r = 0; r < 16; ++r) {
      const int ki = (r & 3) + 8 * (r >> 2) + 4 * h;
      if (!((mb.x >> ki) & 1u)) s0[r] = -1e30f;
      if (!((mb.y >> ki) & 1u)) s1[r] = -1e30f;
    }
  }
  if (kv0 + 63 > q0x) {
    const int q = q0x + l31;
#pragma unroll
    for (int r = 0; r < 16; ++r) {
      const int ki = kv0 + (r & 3) + 8 * (r >> 2) + 4 * h;
      if (ki > q) s0[r] = -1e30f;
      if (ki + 32 > q) s1[r] = -1e30f;
    }
  }
#pragma unroll
  for (int r = 0; r < 16; ++r) {
    s0[r] = __builtin_amdgcn_exp2f(__builtin_fmaf(s0[r], LOG2E, -MB2));
    s1[r] = __builtin_amdgcn_exp2f(__builtin_fmaf(s1[r], LOG2E, -MB2));
  }
  float ts[8];
#pragma unroll
  for (int r = 0; r < 8; ++r)
    ts[r] = (s0[2 * r] + s0[2 * r + 1]) + (s1[2 * r] + s1[2 * r + 1]);
  float ps = ((ts[0] + ts[1]) + (ts[2] + ts[3])) + ((ts[4] + ts[5]) + (ts[6] + ts[7]));
  ps += __shfl_xor(ps, 32);
  lrow += ps;
#pragma unroll
  for (int m = 0; m < 4; ++m)
#pragma unroll
    for (int j = 0; j < 2; ++j) {
      pk0[m][j] = cvt_pk_bf16(s0[4 * m + 2 * j], s0[4 * m + 2 * j + 1]);
      pk1[m][j] = cvt_pk_bf16(s1[4 * m + 2 * j], s1[4 * m + 2 * j + 1]);
    }
}

__device__ __forceinline__ void pv_acc(
    const unsigned (&pk0)[4][2], const unsigned (&pk1)[4][2],
    const bf16x8 (&vf0)[4], const bf16x8 (&vf1)[4], int h,
    f32x16& o0, f32x16& o1) {
#pragma unroll
  for (int kc = 0; kc < 4; ++kc) {
    const unsigned (&pkk)[4][2] = (kc < 2) ? pk0 : pk1;
    const int c1 = (kc & 1) * 2;
    const unsigned v0 = h ? pkk[c1][0] : pkk[c1 + 1][0];
    const unsigned v1 = h ? pkk[c1][1] : pkk[c1 + 1][1];
    const unsigned r0 = (unsigned)__shfl_xor((int)v0, 32);
    const unsigned r1 = (unsigned)__shfl_xor((int)v1, 32);
    union { unsigned u[4]; bf16x8 v; } af;
    af.u[0] = h ? r0 : pkk[c1][0];
    af.u[1] = h ? r1 : pkk[c1][1];
    af.u[2] = h ? pkk[c1 + 1][0] : r0;
    af.u[3] = h ? pkk[c1 + 1][1] : r1;
    __builtin_amdgcn_s_setprio(1);
    o0 = MFMA32(af.v, vf0[kc], o0);
    o1 = MFMA32(af.v, vf1[kc], o1);
    __builtin_amdgcn_s_setprio(0);
  }
}

__global__ void k_attn(
    const unsigned short* __restrict__ Q, const unsigned short* __restrict__ Kb,
    const unsigned short* __restrict__ Vt, const unsigned int* __restrict__ mbits,
    unsigned short* __restrict__ pO, float* __restrict__ pL,
    unsigned short* __restrict__ AO) {
  const int tid = threadIdx.x;
  const int lane = tid & 63;
  const int w = tid >> 6;               // wave -> row-group within quad
  const int l31 = lane & 31;
  const int h = lane >> 5;
  const int lo = l31 * 16 + h * 8;
  // blockIdx -> (xcd-local bh, quad G, chunk c); heavy first (LPT)
  const int f = blockIdx.x;             // 0..479
  const int xcd = f & 7;
  const int i = f >> 3;                 // 0..59
  const int hl = i % 3;
  const int j = i / 3;                  // 0..19
  const int bh = xcd * 3 + hl;
  int G, c;
  if (j < 4)        { G = 7; c = j; }
  else if (j < 8)   { G = 6; c = j - 4; }
  else if (j < 11)  { G = 5; c = j - 8; }
  else if (j < 14)  { G = 4; c = j - 11; }
  else if (j < 16)  { G = 3; c = j - 14; }
  else if (j < 18)  { G = 2; c = j - 16; }
  else if (j == 18) { G = 1; c = 0; }
  else              { G = 0; c = 0; }
  const int k = 4 * G + w;              // row-group 0..31 (q rows [64k, 64k+64))
  int cb;
  if (k < 8)       cb = k;
  else if (k < 16) cb = 8 + 2 * (k - 8);
  else if (k < 24) cb = 24 + 3 * (k - 16);
  else             cb = 48 + 4 * (k - 24);
  const int pidx = bh * 80 + cb + c;

  const int b = bh / HH;
  const int hd = bh - b * HH;
  const int q0 = k * 64;                // A block rows q0.., B block rows q0+32..
  const int nt = k + 1;
  const int t0 = c * 8;
  const int t1 = (t0 + 8 < nt) ? t0 + 8 : nt;

  const unsigned short* Qh = Q + (size_t)bh * BH_STRIDE;
  const unsigned short* Kh = Kb + (size_t)bh * BH_STRIDE;
  const unsigned short* Vh = Vt + (size_t)bh * BH_STRIDE;
  const unsigned int* mbp = mbits + b * 64;

  bf16x8 qfA[4], qfB[4];
  {
    const unsigned short* qp = Qh + (size_t)2 * k * 2048 + lo;
#pragma unroll
    for (int dg = 0; dg < 4; ++dg) {
      qfA[dg] = *reinterpret_cast<const bf16x8*>(&qp[dg * 512]);
      qfB[dg] = *reinterpret_cast<const bf16x8*>(&qp[2048 + dg * 512]);
    }
  }

  f32x16 oA0 = {}, oA1 = {}, oB0 = {}, oB1 = {};
  float lA = 0.f, lB = 0.f;

  bf16x8 kf[2][4];
  loadk(kf, Kh, t0 * 64, lo);

  for (int t = t0; t < t1; ++t) {
    // V tile t (consumed after both softmaxes - latency hidden)
    const unsigned short* vp = Vh + t * 4096 + lo;
    bf16x8 vf0[4], vf1[4];
#pragma unroll
    for (int kc = 0; kc < 4; ++kc) {
      vf0[kc] = *reinterpret_cast<const bf16x8*>(&vp[kc * 1024]);
      vf1[kc] = *reinterpret_cast<const bf16x8*>(&vp[kc * 1024 + 512]);
    }
    const uint2 mbt = *reinterpret_cast<const uint2*>(&mbp[t * 2]);

    // QK^T for q-block A
    f32x16 s0 = {}, s1 = {};
    __builtin_amdgcn_s_setprio(1);
#pragma unroll
    for (int dg = 0; dg < 4; ++dg) s0 = MFMA32(kf[0][dg], qfA[dg], s0);
#pragma unroll
    for (int dg = 0; dg < 4; ++dg) s1 = MFMA32(kf[1][dg], qfA[dg], s1);
    __builtin_amdgcn_s_setprio(0);
    unsigned pkA0[4][2], pkA1[4][2];
    softmax_pack(s0, s1, mbt, t * 64, q0, l31, h, lA, pkA0, pkA1);

    // QK^T for q-block B (kf still live)
    f32x16 u0 = {}, u1 = {};
    __builtin_amdgcn_s_setprio(1);
#pragma unroll
    for (int dg = 0; dg < 4; ++dg) u0 = MFMA32(kf[0][dg], qfB[dg], u0);
#pragma unroll
    for (int dg = 0; dg < 4; ++dg) u1 = MFMA32(kf[1][dg], qfB[dg], u1);
    __builtin_amdgcn_s_setprio(0);
    unsigned pkB0[4][2], pkB1[4][2];
    softmax_pack(u0, u1, mbt, t * 64, q0 + 32, l31, h, lB, pkB0, pkB1);

    // kf free -> prefetch K(t+1); latency covered by PV below
    if (t + 1 < t1) loadk(kf, Kh, (t + 1) * 64, lo);

    pv_acc(pkA0, pkA1, vf0, vf1, h, oA0, oA1);
    pv_acc(pkB0, pkB1, vf0, vf1, h, oB0, oB1);
  }

  if (t0 == 0 && t1 == nt) {
    // solo chunk (k <= 7): normalize and write AO directly
    const float rlA = 1.0f / lA;
    const float rlB = 1.0f / lB;
#pragma unroll
    for (int r = 0; r < 16; ++r) {
      const int crow = (r & 3) + 8 * (r >> 2) + 4 * h;
      const float rbA = __shfl(rlA, crow);
      const float rbB = __shfl(rlB, crow);
      const size_t baseA = (size_t)(b * TT + q0 + crow) * CC + hd * DD;
      const size_t baseB = (size_t)(b * TT + q0 + 32 + crow) * CC + hd * DD;
      AO[baseA + l31] = f2bf(oA0[r] * rbA);
      AO[baseA + 32 + l31] = f2bf(oA1[r] * rbA);
      AO[baseB + l31] = f2bf(oB0[r] * rbB);
      AO[baseB + 32 + l31] = f2bf(oB1[r] * rbB);
    }
  } else {
    // bf16 partials: pO[pidx][64 rows][64 cols]
    unsigned short* po = pO + (size_t)pidx * 4096;
#pragma unroll
    for (int r = 0; r < 16; ++r) {
      const int crow = (r & 3) + 8 * (r >> 2) + 4 * h;
      po[crow * 64 + l31] = f2bf(oA0[r]);
      po[crow * 64 + 32 + l31] = f2bf(oA1[r]);
      po[(32 + crow) * 64 + l31] = f2bf(oB0[r]);
      po[(32 + crow) * 64 + 32 + l31] = f2bf(oB1[r]);
    }
    if (lane < 32) {
      pL[pidx * 64 + lane] = lA;
      pL[pidx * 64 + 32 + lane] = lB;
    }
  }
}

// ---------- phase 2: merge chunk partials for row-groups k>=8 ----------
__global__ __launch_bounds__(256) void k_merge(
    const unsigned short* __restrict__ pO, const float* __restrict__ pL,
    unsigned short* __restrict__ AO) {
  const int kk = 8 + blockIdx.x;        // 8..31
  const int bh = blockIdx.y;
  const int b = bh / HH, hd = bh - b * HH;
  const int nch = (kk + 8) >> 3;        // ceil((kk+1)/8)
  int cb;
  if (kk < 16)      cb = 8 + 2 * (kk - 8);
  else if (kk < 24) cb = 24 + 3 * (kk - 16);
  else              cb = 48 + 4 * (kk - 24);
  const int p0 = bh * 80 + cb;

  const int q = threadIdx.x >> 2;       // 0..63
  const int d0 = (threadIdx.x & 3) * 16;

  float lst = 0.f;
#pragma unroll
  for (int c = 0; c < 4; ++c)
    if (c < nch) lst += pL[(p0 + c) * 64 + q];
  const float inv = 1.0f / lst;

  float acc[16] = {};
#pragma unroll
  for (int c = 0; c < 4; ++c) {
    if (c < nch) {
      const unsigned short* po = pO + (size_t)(p0 + c) * 4096 + q * 64 + d0;
      union { uint4 v; unsigned short u[8]; } rd0, rd1;
      rd0.v = *reinterpret_cast<const uint4*>(po);
      rd1.v = *reinterpret_cast<const uint4*>(po + 8);
#pragma unroll
      for (int jj = 0; jj < 8; ++jj) {
        acc[jj] += bf2f(rd0.u[jj]);
        acc[8 + jj] += bf2f(rd1.u[jj]);
      }
    }
  }
  union { unsigned short u[8]; uint4 v; } ov0, ov1;
#pragma unroll
  for (int jj = 0; jj < 8; ++jj) {
    ov0.u[jj] = f2bf(acc[jj] * inv);
    ov1.u[jj] = f2bf(acc[8 + jj] * inv);
  }
  unsigned short* dst = &AO[(size_t)(b * TT + kk * 64 + q) * CC + hd * DD + d0];
  *reinterpret_cast<uint4*>(dst) = ov0.v;
  *reinterpret_cast<uint4*>(dst + 8) = ov1.v;
}

extern "C" void kernel_launch(void* const* d_in, const int* in_sizes, int n_in,
                              void* d_out, int out_size, void* d_ws, size_t ws_size,
                              hipStream_t stream) {
  const float* x   = (const float*)d_in[0];
  const int* mask  = (const int*)d_in[1];
  const float* Wa  = (const float*)d_in[2];
  const float* ba  = (const float*)d_in[3];
  const float* Wp  = (const float*)d_in[4];
  const float* bp  = (const float*)d_in[5];
  float* out = (float*)d_out;

  char* ws = (char*)d_ws;
  unsigned short* Xb  = (unsigned short*)(ws);                 // [4096][768]
  unsigned short* WaT = (unsigned short*)(ws + 6291456);       // [2304][768]
  unsigned short* WpT = (unsigned short*)(ws + 9830400);       // [768][768]
  unsigned short* Qb  = (unsigned short*)(ws + 11010048);      // frag layout
  unsigned short* Kb  = (unsigned short*)(ws + 17301504);      // frag layout
  unsigned short* Vt  = (unsigned short*)(ws + 23592960);      // frag layout
  unsigned short* AO  = (unsigned short*)(ws + 29884416);      // [4096][768]
  unsigned int*   Mb  = (unsigned int*)(ws + 36175872);        // [2][64] bitmask
  float*          pL  = (float*)(ws + 36667904);               // [1920][64] f32
  unsigned short* pO  = (unsigned short*)(ws + 37159424);      // [1920][64][64] bf16

  k_prep<<<dim3(PREP_CVT + PREP_TR1 + PREP_TR2 + 1), dim3(256), 0, stream>>>(
      x, Xb, Wa, WaT, Wp, WpT, mask, Mb);

  k_gemm<1, 128><<<dim3(MM / 128, N1 / 128), dim3(256), 0, stream>>>(
      Xb, WaT, ba, nullptr, N1, CC, Qb, Kb, Vt);

  k_attn<<<dim3(480), dim3(256), 0, stream>>>(Qb, Kb, Vt, Mb, pO, pL, AO);
  k_merge<<<dim3(24, BB * HH), dim3(256), 0, stream>>>(pO, pL, AO);

  k_gemm<0, 64><<<dim3(MM / 128, CC / 64), dim3(256), 0, stream>>>(
      AO, WpT, bp, out, CC, CC, nullptr, nullptr, nullptr);
}

// Round 14
// 213.186 us; speedup vs baseline: 1.2041x; 1.2041x over previous
//
#include <hip/hip_runtime.h>

typedef __attribute__((ext_vector_type(8))) short bf16x8;
typedef __attribute__((ext_vector_type(4))) float f32x4;
typedef __attribute__((ext_vector_type(16))) float f32x16;

#define MFMA16(a, b, c) __builtin_amdgcn_mfma_f32_16x16x32_bf16(a, b, c, 0, 0, 0)
#define MFMA32(a, b, c) __builtin_amdgcn_mfma_f32_32x32x16_bf16(a, b, c, 0, 0, 0)
#define LOG2E 1.4426950408889634f
#define MB2 46.16624868f   // 32 * log2(e): fixed softmax shift

// Problem constants
#define BB 2
#define TT 2048
#define CC 768
#define HH 12
#define DD 64
#define MM (BB * TT)      // 4096
#define N1 (3 * CC)       // 2304
#define BH_STRIDE 131072  // TT*DD shorts per bh

static __device__ __forceinline__ unsigned short f2bf(float f) {
  union { float f; unsigned u; } v; v.f = f;
  unsigned r = (v.u + 0x7FFFu + ((v.u >> 16) & 1u)) >> 16;
  return (unsigned short)r;
}

static __device__ __forceinline__ float bf2f(unsigned short s) {
  union { unsigned u; float f; } v; v.u = ((unsigned)s) << 16;
  return v.f;
}

static __device__ __forceinline__ unsigned cvt_pk_bf16(float lo, float hi) {
  unsigned r;
  asm("v_cvt_pk_bf16_f32 %0, %1, %2" : "=v"(r) : "v"(lo), "v"(hi));
  return r;
}

static __device__ __forceinline__ void gload_lds16(const void* g, void* l) {
  __builtin_amdgcn_global_load_lds(
      (const __attribute__((address_space(1))) void*)g,
      (__attribute__((address_space(3))) void*)l, 16, 0, 0);
}

static __device__ __forceinline__ int cbof(int qb) {
  if (qb < 16) return qb;
  if (qb < 32) return 16 + 2 * (qb - 16);
  if (qb < 48) return 48 + 3 * (qb - 32);
  return 96 + 4 * (qb - 48);
}

// ---------- fused prep ----------
#define PREP_CVT 3072
#define PREP_TR1 1728
#define PREP_TR2 576
__global__ __launch_bounds__(256) void k_prep(
    const float* __restrict__ x, unsigned short* __restrict__ Xb,
    const float* __restrict__ Wa, unsigned short* __restrict__ WaT,
    const float* __restrict__ Wp, unsigned short* __restrict__ WpT,
    const int* __restrict__ mask, unsigned int* __restrict__ mb,
    unsigned int* __restrict__ cnt) {
  __shared__ float tile[32][33];
  const int bid = blockIdx.x;
  const int tid = threadIdx.x;
  if (bid < PREP_CVT) {
    const int i = bid * 256 + tid;
    float4 v = reinterpret_cast<const float4*>(x)[i];
    ushort4 r;
    r.x = f2bf(v.x); r.y = f2bf(v.y); r.z = f2bf(v.z); r.w = f2bf(v.w);
    reinterpret_cast<ushort4*>(Xb)[i] = r;
  } else if (bid < PREP_CVT + PREP_TR1 + PREP_TR2) {
    const bool first = bid < PREP_CVT + PREP_TR1;
    const int b = first ? bid - PREP_CVT : bid - PREP_CVT - PREP_TR1;
    const int nb = first ? 72 : 24;
    const int N = first ? N1 : CC;
    const float* W = first ? Wa : Wp;
    unsigned short* Wt = first ? WaT : WpT;
    const int n0 = (b % nb) * 32, k0 = (b / nb) * 32;
    const int tx = tid & 31, ty = tid >> 5;
#pragma unroll
    for (int i = 0; i < 4; ++i)
      tile[ty + i * 8][tx] = W[(size_t)(k0 + ty + i * 8) * N + n0 + tx];
    __syncthreads();
#pragma unroll
    for (int i = 0; i < 4; ++i)
      Wt[(size_t)(n0 + ty + i * 8) * CC + k0 + tx] = f2bf(tile[tx][ty + i * 8]);
  } else {
    if (tid < 128) {
      unsigned bits = 0;
      const int* p = mask + tid * 32;
#pragma unroll
      for (int j = 0; j < 32; ++j) bits |= (p[j] != 0 ? 1u : 0u) << j;
      mb[tid] = bits;
    }
    for (int z = tid; z < 384; z += 256) cnt[z] = 0;  // merge counters
  }
}

// ---------- bf16 GEMM: 128xBN tile, BK=32, 3-buffer counted-vmcnt pipeline ----------
template <int MODE, int BN>
__global__ __launch_bounds__(256) void k_gemm(
    const unsigned short* __restrict__ A, const unsigned short* __restrict__ Bt,
    const float* __restrict__ bias, float* __restrict__ Cout, int N, int K,
    unsigned short* __restrict__ Qb, unsigned short* __restrict__ Kb,
    unsigned short* __restrict__ Vt) {
  constexpr int NI = BN / 32;
  __shared__ __align__(16) unsigned short As[3][128 * 32];
  __shared__ __align__(16) unsigned short Bs[3][BN * 32];
  const int tid = threadIdx.x;
  const int lane = tid & 63;
  const int wid = tid >> 6;
  const int l15 = lane & 15, l4 = lane >> 4;
  const int wr = wid >> 1, wc = wid & 1;
  const int brow = blockIdx.x * 128, bcol = blockIdx.y * BN;

  f32x4 acc[4][NI] = {};

  const int srow = tid >> 2;
  const int usrc = (tid & 3) ^ ((tid >> 3) & 3);
  const unsigned short* gA0 = A + (size_t)(brow + srow) * K + usrc * 8;
  const unsigned short* gA1 = gA0 + (size_t)64 * K;
  const unsigned short* gB0 = Bt + (size_t)(bcol + srow) * K + usrc * 8;
  const unsigned short* gB1 = (BN == 128) ? gB0 + (size_t)64 * K : gB0;
  const int dslot = tid * 8;

  const int NT = K / 32;

#define STAGE(t, buf)                                       \
  do {                                                      \
    const int ko = (t) * 32;                                \
    gload_lds16(gA0 + ko, &As[buf][dslot]);                 \
    gload_lds16(gA1 + ko, &As[buf][dslot + 2048]);          \
    gload_lds16(gB0 + ko, &Bs[buf][dslot]);                 \
    if (BN == 128) gload_lds16(gB1 + ko, &Bs[buf][dslot + 2048]); \
  } while (0)

  const int swz = (l4 ^ ((l15 >> 1) & 3)) * 8;
  const int arow = wr * 64 + l15;
  const int brow2 = wc * (BN / 2) + l15;

  STAGE(0, 0);
  STAGE(1, 1);

  int cur = 0;
  for (int t = 0; t < NT - 1; ++t) {
    if (BN == 128) asm volatile("s_waitcnt vmcnt(4)" ::: "memory");
    else           asm volatile("s_waitcnt vmcnt(3)" ::: "memory");
    __builtin_amdgcn_s_barrier();
    if (t + 2 < NT) {
      int nb = cur + 2; if (nb >= 3) nb -= 3;
      STAGE(t + 2, nb);
    }
    bf16x8 af[4], bfr[NI];
#pragma unroll
    for (int mi = 0; mi < 4; ++mi)
      af[mi] = *reinterpret_cast<const bf16x8*>(&As[cur][(arow + mi * 16) * 32 + swz]);
#pragma unroll
    for (int ni = 0; ni < NI; ++ni)
      bfr[ni] = *reinterpret_cast<const bf16x8*>(&Bs[cur][(brow2 + ni * 16) * 32 + swz]);
#pragma unroll
    for (int mi = 0; mi < 4; ++mi)
#pragma unroll
      for (int ni = 0; ni < NI; ++ni)
        acc[mi][ni] = MFMA16(af[mi], bfr[ni], acc[mi][ni]);
    cur = (cur == 2) ? 0 : cur + 1;
  }
  asm volatile("s_waitcnt vmcnt(0)" ::: "memory");
  __builtin_amdgcn_s_barrier();
  {
    bf16x8 af[4], bfr[NI];
#pragma unroll
    for (int mi = 0; mi < 4; ++mi)
      af[mi] = *reinterpret_cast<const bf16x8*>(&As[cur][(arow + mi * 16) * 32 + swz]);
#pragma unroll
    for (int ni = 0; ni < NI; ++ni)
      bfr[ni] = *reinterpret_cast<const bf16x8*>(&Bs[cur][(brow2 + ni * 16) * 32 + swz]);
#pragma unroll
    for (int mi = 0; mi < 4; ++mi)
#pragma unroll
      for (int ni = 0; ni < NI; ++ni)
        acc[mi][ni] = MFMA16(af[mi], bfr[ni], acc[mi][ni]);
  }
#undef STAGE

#pragma unroll
  for (int mi = 0; mi < 4; ++mi) {
    const int m0 = brow + wr * 64 + mi * 16 + l4 * 4;
#pragma unroll
    for (int ni = 0; ni < NI; ++ni) {
      const int n = bcol + wc * (BN / 2) + ni * 16 + l15;
      const float bv = bias[n];
      if (MODE == 0) {
#pragma unroll
        for (int r = 0; r < 4; ++r)
          Cout[(size_t)(m0 + r) * N + n] = acc[mi][ni][r] + bv;
      } else {
        const int sec = n / CC;
        const int nn = n - sec * CC;
        const int hh = nn >> 6, d = nn & 63;
        const int b = m0 >> 11;
        const int t0 = m0 & 2047;
        const size_t hbase = (size_t)(b * HH + hh) * BH_STRIDE;
        if (sec == 0) {
#pragma unroll
          for (int r = 0; r < 4; ++r) {
            const int t = t0 + r;
            Qb[hbase + ((t >> 5) * 4 + (d >> 4)) * 512 + (t & 31) * 16 + (d & 15)] =
                f2bf((acc[mi][ni][r] + bv) * 0.125f);
          }
        } else if (sec == 1) {
#pragma unroll
          for (int r = 0; r < 4; ++r) {
            const int t = t0 + r;
            Kb[hbase + ((t >> 5) * 4 + (d >> 4)) * 512 + (t & 31) * 16 + (d & 15)] =
                f2bf(acc[mi][ni][r] + bv);
          }
        } else {
          ushort4 pk;
          pk.x = f2bf(acc[mi][ni][0] + bv);
          pk.y = f2bf(acc[mi][ni][1] + bv);
          pk.z = f2bf(acc[mi][ni][2] + bv);
          pk.w = f2bf(acc[mi][ni][3] + bv);
          *reinterpret_cast<ushort4*>(
              &Vt[hbase + ((t0 >> 6) * 4 + ((t0 >> 4) & 3)) * 1024 + d * 16 + (t0 & 15)]) = pk;
        }
      }
    }
  }
}

// ---------- causal flash attention (r12 body) + fused last-block merge ----------
__device__ __forceinline__ void loadk(bf16x8 (&dst)[2][4], const unsigned short* Kh,
                                      int kv0, int lo) {
  const unsigned short* kp = Kh + (kv0 >> 5) * 2048 + lo;
#pragma unroll
  for (int kg = 0; kg < 2; ++kg)
#pragma unroll
    for (int dg = 0; dg < 4; ++dg)
      dst[kg][dg] = *reinterpret_cast<const bf16x8*>(&kp[kg * 2048 + dg * 512]);
}

__device__ __forceinline__ void attn_tile(
    int kv0, const bf16x8 (&kf)[2][4], uint2 mb, const bf16x8 (&qf)[4],
    const unsigned short* __restrict__ Vh, int q0, int l31, int h, int lo,
    f32x16& o0, f32x16& o1, float& lrow) {
  const unsigned short* vp = Vh + (kv0 >> 6) * 4096 + lo;
  bf16x8 vf0[4], vf1[4];
#pragma unroll
  for (int kc = 0; kc < 4; ++kc) {
    vf0[kc] = *reinterpret_cast<const bf16x8*>(&vp[kc * 1024]);
    vf1[kc] = *reinterpret_cast<const bf16x8*>(&vp[kc * 1024 + 512]);
  }

  f32x16 s0 = {}, s1 = {};
  __builtin_amdgcn_s_setprio(1);
#pragma unroll
  for (int dg = 0; dg < 4; ++dg) s0 = MFMA32(kf[0][dg], qf[dg], s0);
#pragma unroll
  for (int dg = 0; dg < 4; ++dg) s1 = MFMA32(kf[1][dg], qf[dg], s1);
  __builtin_amdgcn_s_setprio(0);

  if ((mb.x & mb.y) != 0xffffffffu) {
#pragma unroll
    for (int r = 0; r < 16; ++r) {
      const int ki = (r & 3) + 8 * (r >> 2) + 4 * h;
      if (!((mb.x >> ki) & 1u)) s0[r] = -1e30f;
      if (!((mb.y >> ki) & 1u)) s1[r] = -1e30f;
    }
  }
  if (kv0 + 63 > q0) {
    const int q = q0 + l31;
#pragma unroll
    for (int r = 0; r < 16; ++r) {
      const int ki = kv0 + (r & 3) + 8 * (r >> 2) + 4 * h;
      if (ki > q) s0[r] = -1e30f;
      if (ki + 32 > q) s1[r] = -1e30f;
    }
  }

#pragma unroll
  for (int r = 0; r < 16; ++r) {
    s0[r] = __builtin_amdgcn_exp2f(__builtin_fmaf(s0[r], LOG2E, -MB2));
    s1[r] = __builtin_amdgcn_exp2f(__builtin_fmaf(s1[r], LOG2E, -MB2));
  }
  float ts[8];
#pragma unroll
  for (int r = 0; r < 8; ++r)
    ts[r] = (s0[2 * r] + s0[2 * r + 1]) + (s1[2 * r] + s1[2 * r + 1]);
  float ps = ((ts[0] + ts[1]) + (ts[2] + ts[3])) + ((ts[4] + ts[5]) + (ts[6] + ts[7]));
  ps += __shfl_xor(ps, 32);
  lrow += ps;

  unsigned pk0[4][2], pk1[4][2];
#pragma unroll
  for (int m = 0; m < 4; ++m)
#pragma unroll
    for (int j = 0; j < 2; ++j) {
      pk0[m][j] = cvt_pk_bf16(s0[4 * m + 2 * j], s0[4 * m + 2 * j + 1]);
      pk1[m][j] = cvt_pk_bf16(s1[4 * m + 2 * j], s1[4 * m + 2 * j + 1]);
    }

#pragma unroll
  for (int kc = 0; kc < 4; ++kc) {
    const unsigned (&pkk)[4][2] = (kc < 2) ? pk0 : pk1;
    const int c1 = (kc & 1) * 2;
    const unsigned v0 = h ? pkk[c1][0] : pkk[c1 + 1][0];
    const unsigned v1 = h ? pkk[c1][1] : pkk[c1 + 1][1];
    const unsigned r0 = (unsigned)__shfl_xor((int)v0, 32);
    const unsigned r1 = (unsigned)__shfl_xor((int)v1, 32);
    union { unsigned u[4]; bf16x8 v; } af;
    af.u[0] = h ? r0 : pkk[c1][0];
    af.u[1] = h ? r1 : pkk[c1][1];
    af.u[2] = h ? pkk[c1 + 1][0] : r0;
    af.u[3] = h ? pkk[c1 + 1][1] : r1;
    __builtin_amdgcn_s_setprio(1);
    o0 = MFMA32(af.v, vf0[kc], o0);
    o1 = MFMA32(af.v, vf1[kc], o1);
    __builtin_amdgcn_s_setprio(0);
  }
}

__global__ __launch_bounds__(256, 2) void k_attn(
    const unsigned short* __restrict__ Q, const unsigned short* __restrict__ Kb,
    const unsigned short* __restrict__ Vt, const unsigned int* __restrict__ mbits,
    unsigned short* __restrict__ pO, float* __restrict__ pL,
    unsigned short* __restrict__ AO, unsigned int* __restrict__ cnt) {
  __shared__ unsigned s_old;
  const int tid = threadIdx.x;
  const int lane = tid & 63;
  const int w = tid >> 6;               // wave -> q-block within quad
  const int l31 = lane & 31;
  const int h = lane >> 5;
  const int lo = l31 * 16 + h * 8;
  // blockIdx -> (xcd-local bh, quad g, chunk c); heavy chunks first (LPT)
  const int f = blockIdx.x;             // 0..959
  const int xcd = f & 7;
  const int i = f >> 3;                 // 0..119
  const int hl = i % 3;
  const int j = i / 3;                  // 0..39
  const int bh = xcd * 3 + hl;
  int g, c;
  if (j < 16)      { g = 15 - (j >> 2); c = j & 3; }
  else if (j < 28) { const int u = j - 16; g = 11 - u / 3; c = u % 3; }
  else if (j < 36) { const int u = j - 28; g = 7 - (u >> 1); c = u & 1; }
  else             { g = 3 - (j - 36); c = 0; }
  const int nc = (g >= 12) ? 4 : (g >= 8) ? 3 : (g >= 4) ? 2 : 1;  // chunks/quad
  const int qb = 4 * g + w;
  const int pidx = bh * 160 + cbof(qb) + c;

  const int b = bh / HH;
  const int hd = bh - b * HH;
  const int q0 = qb * 32;
  const int nt = qb / 2 + 1;
  const int t0 = c * 8;
  const int t1 = (t0 + 8 < nt) ? t0 + 8 : nt;

  const unsigned short* Qh = Q + (size_t)bh * BH_STRIDE;
  const unsigned short* Kh = Kb + (size_t)bh * BH_STRIDE;
  const unsigned short* Vh = Vt + (size_t)bh * BH_STRIDE;
  const unsigned int* mbp = mbits + b * 64;

  bf16x8 qf[4];
  {
    const unsigned short* qp = Qh + (q0 >> 5) * 2048 + lo;
#pragma unroll
    for (int dg = 0; dg < 4; ++dg)
      qf[dg] = *reinterpret_cast<const bf16x8*>(&qp[dg * 512]);
  }

  f32x16 o0 = {}, o1 = {};
  float lrow = 0.f;

  bf16x8 kfA[2][4], kfB[2][4];
  uint2 mbA, mbB;
  loadk(kfA, Kh, t0 * 64, lo);
  mbA = *reinterpret_cast<const uint2*>(&mbp[t0 * 2]);

  int t = t0;
  while (true) {
    if (t + 1 < t1) {
      loadk(kfB, Kh, (t + 1) * 64, lo);
      mbB = *reinterpret_cast<const uint2*>(&mbp[(t + 1) * 2]);
    }
    attn_tile(t * 64, kfA, mbA, qf, Vh, q0, l31, h, lo, o0, o1, lrow);
    ++t; if (t >= t1) break;
    if (t + 1 < t1) {
      loadk(kfA, Kh, (t + 1) * 64, lo);
      mbA = *reinterpret_cast<const uint2*>(&mbp[(t + 1) * 2]);
    }
    attn_tile(t * 64, kfB, mbB, qf, Vh, q0, l31, h, lo, o0, o1, lrow);
    ++t; if (t >= t1) break;
  }

  if (nc == 1) {
    // solo quad: every wave covers its whole row range; write AO directly
    const float rl = 1.0f / lrow;
#pragma unroll
    for (int r = 0; r < 16; ++r) {
      const int crow = (r & 3) + 8 * (r >> 2) + 4 * h;
      const float rb = __shfl(rl, crow);
      const size_t base = (size_t)(b * TT + q0 + crow) * CC + hd * DD;
      AO[base + l31] = f2bf(o0[r] * rb);
      AO[base + 32 + l31] = f2bf(o1[r] * rb);
    }
    return;
  }

  // chunked quad: write bf16 partials, then last-block merge
  {
    unsigned short* po = pO + (size_t)pidx * 2048;
#pragma unroll
    for (int r = 0; r < 16; ++r) {
      const int crow = (r & 3) + 8 * (r >> 2) + 4 * h;
      po[crow * 64 + l31] = f2bf(o0[r]);
      po[crow * 64 + 32 + l31] = f2bf(o1[r]);
    }
    if (lane < 32) {
      pL[pidx * 32 + lane] = lrow;
    }
  }
  __threadfence();                       // publish partials device-wide
  __syncthreads();                       // all waves published
  if (tid == 0) s_old = atomicAdd(&cnt[bh * 16 + g], 1u);
  __syncthreads();
  if (s_old != (unsigned)(nc - 1)) return;
  __threadfence();                       // acquire: see other blocks' partials

  // merge all 4 q-blocks of this quad (fixed chunk order -> deterministic)
  const int q = tid >> 3;                // 0..31
  const int d0 = (tid & 7) * 8;
#pragma unroll
  for (int w2 = 0; w2 < 4; ++w2) {
    const int qb2 = 4 * g + w2;
    const int p0 = bh * 160 + cbof(qb2);
    float lst = 0.f;
    for (int cc = 0; cc < nc; ++cc) lst += pL[(p0 + cc) * 32 + q];
    const float inv = 1.0f / lst;
    float acc[8] = {};
    for (int cc = 0; cc < nc; ++cc) {
      const unsigned short* po = pO + ((size_t)(p0 + cc) * 32 + q) * 64 + d0;
      union { uint4 v; unsigned short u[8]; } rd;
      rd.v = *reinterpret_cast<const uint4*>(po);
#pragma unroll
      for (int jj = 0; jj < 8; ++jj) acc[jj] += bf2f(rd.u[jj]);
    }
    union { unsigned short u[8]; uint4 v; } ov;
#pragma unroll
    for (int jj = 0; jj < 8; ++jj) ov.u[jj] = f2bf(acc[jj] * inv);
    *reinterpret_cast<uint4*>(
        &AO[(size_t)(b * TT + qb2 * 32 + q) * CC + hd * DD + d0]) = ov.v;
  }
}

extern "C" void kernel_launch(void* const* d_in, const int* in_sizes, int n_in,
                              void* d_out, int out_size, void* d_ws, size_t ws_size,
                              hipStream_t stream) {
  const float* x   = (const float*)d_in[0];
  const int* mask  = (const int*)d_in[1];
  const float* Wa  = (const float*)d_in[2];
  const float* ba  = (const float*)d_in[3];
  const float* Wp  = (const float*)d_in[4];
  const float* bp  = (const float*)d_in[5];
  float* out = (float*)d_out;

  char* ws = (char*)d_ws;
  unsigned short* Xb  = (unsigned short*)(ws);                 // [4096][768]
  unsigned short* WaT = (unsigned short*)(ws + 6291456);       // [2304][768]
  unsigned short* WpT = (unsigned short*)(ws + 9830400);       // [768][768]
  unsigned short* Qb  = (unsigned short*)(ws + 11010048);      // frag layout
  unsigned short* Kb  = (unsigned short*)(ws + 17301504);      // frag layout
  unsigned short* Vt  = (unsigned short*)(ws + 23592960);      // frag layout
  unsigned short* AO  = (unsigned short*)(ws + 29884416);      // [4096][768]
  unsigned int*   Mb  = (unsigned int*)(ws + 36175872);        // [2][64] bitmask
  float*          pL  = (float*)(ws + 36667904);               // [3840][32] f32
  unsigned short* pO  = (unsigned short*)(ws + 37159424);      // [3840][32][64] bf16
  unsigned int*   Cn  = (unsigned int*)(ws + 52888064);        // [384] counters

  k_prep<<<dim3(PREP_CVT + PREP_TR1 + PREP_TR2 + 1), dim3(256), 0, stream>>>(
      x, Xb, Wa, WaT, Wp, WpT, mask, Mb, Cn);

  k_gemm<1, 128><<<dim3(MM / 128, N1 / 128), dim3(256), 0, stream>>>(
      Xb, WaT, ba, nullptr, N1, CC, Qb, Kb, Vt);

  k_attn<<<dim3(960), dim3(256), 0, stream>>>(Qb, Kb, Vt, Mb, pO, pL, AO, Cn);

  k_gemm<0, 64><<<dim3(MM / 128, CC / 64), dim3(256), 0, stream>>>(
      AO, WpT, bp, out, CC, CC, nullptr, nullptr, nullptr);
}

// Round 15
// 82.513 us; speedup vs baseline: 3.1110x; 2.5837x over previous
//
#include <hip/hip_runtime.h>

typedef __attribute__((ext_vector_type(8))) short bf16x8;
typedef __attribute__((ext_vector_type(4))) float f32x4;
typedef __attribute__((ext_vector_type(16))) float f32x16;

#define MFMA16(a, b, c) __builtin_amdgcn_mfma_f32_16x16x32_bf16(a, b, c, 0, 0, 0)
#define MFMA32(a, b, c) __builtin_amdgcn_mfma_f32_32x32x16_bf16(a, b, c, 0, 0, 0)
#define LOG2E 1.4426950408889634f
#define MB2 46.16624868f   // 32 * log2(e): fixed softmax shift

// Problem constants
#define BB 2
#define TT 2048
#define CC 768
#define HH 12
#define DD 64
#define MM (BB * TT)      // 4096
#define N1 (3 * CC)       // 2304
#define BH_STRIDE 131072  // TT*DD shorts per bh

static __device__ __forceinline__ unsigned short f2bf(float f) {
  union { float f; unsigned u; } v; v.f = f;
  unsigned r = (v.u + 0x7FFFu + ((v.u >> 16) & 1u)) >> 16;
  return (unsigned short)r;
}

static __device__ __forceinline__ float bf2f(unsigned short s) {
  union { unsigned u; float f; } v; v.u = ((unsigned)s) << 16;
  return v.f;
}

static __device__ __forceinline__ unsigned cvt_pk_bf16(float lo, float hi) {
  unsigned r;
  asm("v_cvt_pk_bf16_f32 %0, %1, %2" : "=v"(r) : "v"(lo), "v"(hi));
  return r;
}

static __device__ __forceinline__ void gload_lds16(const void* g, void* l) {
  __builtin_amdgcn_global_load_lds(
      (const __attribute__((address_space(1))) void*)g,
      (__attribute__((address_space(3))) void*)l, 16, 0, 0);
}

// ---------- fused prep ----------
#define PREP_CVT 3072
#define PREP_TR1 1728
#define PREP_TR2 576
__global__ __launch_bounds__(256) void k_prep(
    const float* __restrict__ x, unsigned short* __restrict__ Xb,
    const float* __restrict__ Wa, unsigned short* __restrict__ WaT,
    const float* __restrict__ Wp, unsigned short* __restrict__ WpT,
    const int* __restrict__ mask, unsigned int* __restrict__ mb) {
  __shared__ float tile[32][33];
  const int bid = blockIdx.x;
  const int tid = threadIdx.x;
  if (bid < PREP_CVT) {
    const int i = bid * 256 + tid;
    float4 v = reinterpret_cast<const float4*>(x)[i];
    ushort4 r;
    r.x = f2bf(v.x); r.y = f2bf(v.y); r.z = f2bf(v.z); r.w = f2bf(v.w);
    reinterpret_cast<ushort4*>(Xb)[i] = r;
  } else if (bid < PREP_CVT + PREP_TR1 + PREP_TR2) {
    const bool first = bid < PREP_CVT + PREP_TR1;
    const int b = first ? bid - PREP_CVT : bid - PREP_CVT - PREP_TR1;
    const int nb = first ? 72 : 24;
    const int N = first ? N1 : CC;
    const float* W = first ? Wa : Wp;
    unsigned short* Wt = first ? WaT : WpT;
    const int n0 = (b % nb) * 32, k0 = (b / nb) * 32;
    const int tx = tid & 31, ty = tid >> 5;
#pragma unroll
    for (int i = 0; i < 4; ++i)
      tile[ty + i * 8][tx] = W[(size_t)(k0 + ty + i * 8) * N + n0 + tx];
    __syncthreads();
#pragma unroll
    for (int i = 0; i < 4; ++i)
      Wt[(size_t)(n0 + ty + i * 8) * CC + k0 + tx] = f2bf(tile[tx][ty + i * 8]);
  } else {
    if (tid < 128) {
      unsigned bits = 0;
      const int* p = mask + tid * 32;
#pragma unroll
      for (int j = 0; j < 32; ++j) bits |= (p[j] != 0 ? 1u : 0u) << j;
      mb[tid] = bits;
    }
  }
}

// ---------- bf16 GEMM: 128xBN tile, BK=32, 3-buffer counted-vmcnt pipeline ----------
// No setprio here: m190 measured setprio HURTS barrier-lockstep GEMM.
template <int MODE, int BN>
__global__ __launch_bounds__(256) void k_gemm(
    const unsigned short* __restrict__ A, const unsigned short* __restrict__ Bt,
    const float* __restrict__ bias, float* __restrict__ Cout, int N, int K,
    unsigned short* __restrict__ Qb, unsigned short* __restrict__ Kb,
    unsigned short* __restrict__ Vt) {
  constexpr int NI = BN / 32;
  __shared__ __align__(16) unsigned short As[3][128 * 32];
  __shared__ __align__(16) unsigned short Bs[3][BN * 32];
  const int tid = threadIdx.x;
  const int lane = tid & 63;
  const int wid = tid >> 6;
  const int l15 = lane & 15, l4 = lane >> 4;
  const int wr = wid >> 1, wc = wid & 1;
  const int brow = blockIdx.x * 128, bcol = blockIdx.y * BN;

  f32x4 acc[4][NI] = {};

  const int srow = tid >> 2;
  const int usrc = (tid & 3) ^ ((tid >> 3) & 3);
  const unsigned short* gA0 = A + (size_t)(brow + srow) * K + usrc * 8;
  const unsigned short* gA1 = gA0 + (size_t)64 * K;
  const unsigned short* gB0 = Bt + (size_t)(bcol + srow) * K + usrc * 8;
  const unsigned short* gB1 = (BN == 128) ? gB0 + (size_t)64 * K : gB0;
  const int dslot = tid * 8;

  const int NT = K / 32;

#define STAGE(t, buf)                                       \
  do {                                                      \
    const int ko = (t) * 32;                                \
    gload_lds16(gA0 + ko, &As[buf][dslot]);                 \
    gload_lds16(gA1 + ko, &As[buf][dslot + 2048]);          \
    gload_lds16(gB0 + ko, &Bs[buf][dslot]);                 \
    if (BN == 128) gload_lds16(gB1 + ko, &Bs[buf][dslot + 2048]); \
  } while (0)

  const int swz = (l4 ^ ((l15 >> 1) & 3)) * 8;
  const int arow = wr * 64 + l15;
  const int brow2 = wc * (BN / 2) + l15;

  STAGE(0, 0);
  STAGE(1, 1);

  int cur = 0;
  for (int t = 0; t < NT - 1; ++t) {
    if (BN == 128) asm volatile("s_waitcnt vmcnt(4)" ::: "memory");
    else           asm volatile("s_waitcnt vmcnt(3)" ::: "memory");
    __builtin_amdgcn_s_barrier();
    if (t + 2 < NT) {
      int nb = cur + 2; if (nb >= 3) nb -= 3;
      STAGE(t + 2, nb);
    }
    bf16x8 af[4], bfr[NI];
#pragma unroll
    for (int mi = 0; mi < 4; ++mi)
      af[mi] = *reinterpret_cast<const bf16x8*>(&As[cur][(arow + mi * 16) * 32 + swz]);
#pragma unroll
    for (int ni = 0; ni < NI; ++ni)
      bfr[ni] = *reinterpret_cast<const bf16x8*>(&Bs[cur][(brow2 + ni * 16) * 32 + swz]);
#pragma unroll
    for (int mi = 0; mi < 4; ++mi)
#pragma unroll
      for (int ni = 0; ni < NI; ++ni)
        acc[mi][ni] = MFMA16(af[mi], bfr[ni], acc[mi][ni]);
    cur = (cur == 2) ? 0 : cur + 1;
  }
  asm volatile("s_waitcnt vmcnt(0)" ::: "memory");
  __builtin_amdgcn_s_barrier();
  {
    bf16x8 af[4], bfr[NI];
#pragma unroll
    for (int mi = 0; mi < 4; ++mi)
      af[mi] = *reinterpret_cast<const bf16x8*>(&As[cur][(arow + mi * 16) * 32 + swz]);
#pragma unroll
    for (int ni = 0; ni < NI; ++ni)
      bfr[ni] = *reinterpret_cast<const bf16x8*>(&Bs[cur][(brow2 + ni * 16) * 32 + swz]);
#pragma unroll
    for (int mi = 0; mi < 4; ++mi)
#pragma unroll
      for (int ni = 0; ni < NI; ++ni)
        acc[mi][ni] = MFMA16(af[mi], bfr[ni], acc[mi][ni]);
  }
#undef STAGE

#pragma unroll
  for (int mi = 0; mi < 4; ++mi) {
    const int m0 = brow + wr * 64 + mi * 16 + l4 * 4;
#pragma unroll
    for (int ni = 0; ni < NI; ++ni) {
      const int n = bcol + wc * (BN / 2) + ni * 16 + l15;
      const float bv = bias[n];
      if (MODE == 0) {
#pragma unroll
        for (int r = 0; r < 4; ++r)
          Cout[(size_t)(m0 + r) * N + n] = acc[mi][ni][r] + bv;
      } else {
        const int sec = n / CC;
        const int nn = n - sec * CC;
        const int hh = nn >> 6, d = nn & 63;
        const int b = m0 >> 11;
        const int t0 = m0 & 2047;
        const size_t hbase = (size_t)(b * HH + hh) * BH_STRIDE;
        if (sec == 0) {
#pragma unroll
          for (int r = 0; r < 4; ++r) {
            const int t = t0 + r;
            Qb[hbase + ((t >> 5) * 4 + (d >> 4)) * 512 + (t & 31) * 16 + (d & 15)] =
                f2bf((acc[mi][ni][r] + bv) * 0.125f);
          }
        } else if (sec == 1) {
#pragma unroll
          for (int r = 0; r < 4; ++r) {
            const int t = t0 + r;
            Kb[hbase + ((t >> 5) * 4 + (d >> 4)) * 512 + (t & 31) * 16 + (d & 15)] =
                f2bf(acc[mi][ni][r] + bv);
          }
        } else {
          ushort4 pk;
          pk.x = f2bf(acc[mi][ni][0] + bv);
          pk.y = f2bf(acc[mi][ni][1] + bv);
          pk.z = f2bf(acc[mi][ni][2] + bv);
          pk.w = f2bf(acc[mi][ni][3] + bv);
          *reinterpret_cast<ushort4*>(
              &Vt[hbase + ((t0 >> 6) * 4 + ((t0 >> 4) & 3)) * 1024 + d * 16 + (t0 & 15)]) = pk;
        }
      }
    }
  }
}

// ---------- causal flash attention, phase 1 (fixed-m softmax) ----------
// Block = 4 waves = q-blocks {4g..4g+3} sharing one 8-tile KV chunk (L1 reuse).
// Register-direct K/V loads (fragment-native layout); NO LDS staging.
__device__ __forceinline__ void loadk(bf16x8 (&dst)[2][4], const unsigned short* Kh,
                                      int kv0, int lo) {
  const unsigned short* kp = Kh + (kv0 >> 5) * 2048 + lo;
#pragma unroll
  for (int kg = 0; kg < 2; ++kg)
#pragma unroll
    for (int dg = 0; dg < 4; ++dg)
      dst[kg][dg] = *reinterpret_cast<const bf16x8*>(&kp[kg * 2048 + dg * 512]);
}

__device__ __forceinline__ void attn_tile(
    int kv0, const bf16x8 (&kf)[2][4], uint2 mb, const bf16x8 (&qf)[4],
    const unsigned short* __restrict__ Vh, int q0, int l31, int h, int lo,
    f32x16& o0, f32x16& o1, float& lrow) {
  const unsigned short* vp = Vh + (kv0 >> 6) * 4096 + lo;
  bf16x8 vf0[4], vf1[4];
#pragma unroll
  for (int kc = 0; kc < 4; ++kc) {
    vf0[kc] = *reinterpret_cast<const bf16x8*>(&vp[kc * 1024]);
    vf1[kc] = *reinterpret_cast<const bf16x8*>(&vp[kc * 1024 + 512]);
  }

  f32x16 s0 = {}, s1 = {};
  __builtin_amdgcn_s_setprio(1);
#pragma unroll
  for (int dg = 0; dg < 4; ++dg) s0 = MFMA32(kf[0][dg], qf[dg], s0);
#pragma unroll
  for (int dg = 0; dg < 4; ++dg) s1 = MFMA32(kf[1][dg], qf[dg], s1);
  __builtin_amdgcn_s_setprio(0);

  if ((mb.x & mb.y) != 0xffffffffu) {
#pragma unroll
    for (int r = 0; r < 16; ++r) {
      const int ki = (r & 3) + 8 * (r >> 2) + 4 * h;
      if (!((mb.x >> ki) & 1u)) s0[r] = -1e30f;
      if (!((mb.y >> ki) & 1u)) s1[r] = -1e30f;
    }
  }
  if (kv0 + 63 > q0) {
    const int q = q0 + l31;
#pragma unroll
    for (int r = 0; r < 16; ++r) {
      const int ki = kv0 + (r & 3) + 8 * (r >> 2) + 4 * h;
      if (ki > q) s0[r] = -1e30f;
      if (ki + 32 > q) s1[r] = -1e30f;
    }
  }

#pragma unroll
  for (int r = 0; r < 16; ++r) {
    s0[r] = __builtin_amdgcn_exp2f(__builtin_fmaf(s0[r], LOG2E, -MB2));
    s1[r] = __builtin_amdgcn_exp2f(__builtin_fmaf(s1[r], LOG2E, -MB2));
  }
  float ts[8];
#pragma unroll
  for (int r = 0; r < 8; ++r)
    ts[r] = (s0[2 * r] + s0[2 * r + 1]) + (s1[2 * r] + s1[2 * r + 1]);
  float ps = ((ts[0] + ts[1]) + (ts[2] + ts[3])) + ((ts[4] + ts[5]) + (ts[6] + ts[7]));
  ps += __shfl_xor(ps, 32);
  lrow += ps;

  unsigned pk0[4][2], pk1[4][2];
#pragma unroll
  for (int m = 0; m < 4; ++m)
#pragma unroll
    for (int j = 0; j < 2; ++j) {
      pk0[m][j] = cvt_pk_bf16(s0[4 * m + 2 * j], s0[4 * m + 2 * j + 1]);
      pk1[m][j] = cvt_pk_bf16(s1[4 * m + 2 * j], s1[4 * m + 2 * j + 1]);
    }

#pragma unroll
  for (int kc = 0; kc < 4; ++kc) {
    const unsigned (&pkk)[4][2] = (kc < 2) ? pk0 : pk1;
    const int c1 = (kc & 1) * 2;
    const unsigned v0 = h ? pkk[c1][0] : pkk[c1 + 1][0];
    const unsigned v1 = h ? pkk[c1][1] : pkk[c1 + 1][1];
    const unsigned r0 = (unsigned)__shfl_xor((int)v0, 32);
    const unsigned r1 = (unsigned)__shfl_xor((int)v1, 32);
    union { unsigned u[4]; bf16x8 v; } af;
    af.u[0] = h ? r0 : pkk[c1][0];
    af.u[1] = h ? r1 : pkk[c1][1];
    af.u[2] = h ? pkk[c1 + 1][0] : r0;
    af.u[3] = h ? pkk[c1 + 1][1] : r1;
    __builtin_amdgcn_s_setprio(1);
    o0 = MFMA32(af.v, vf0[kc], o0);
    o1 = MFMA32(af.v, vf1[kc], o1);
    __builtin_amdgcn_s_setprio(0);
  }
}

__global__ __launch_bounds__(256, 2) void k_attn(
    const unsigned short* __restrict__ Q, const unsigned short* __restrict__ Kb,
    const unsigned short* __restrict__ Vt, const unsigned int* __restrict__ mbits,
    unsigned short* __restrict__ pO, float* __restrict__ pL,
    unsigned short* __restrict__ AO) {
  const int tid = threadIdx.x;
  const int lane = tid & 63;
  const int w = tid >> 6;               // wave -> q-block within quad
  const int l31 = lane & 31;
  const int h = lane >> 5;
  const int lo = l31 * 16 + h * 8;
  // blockIdx -> (xcd-local bh, quad g, chunk c); heavy chunks first (LPT)
  const int f = blockIdx.x;             // 0..959
  const int xcd = f & 7;
  const int i = f >> 3;                 // 0..119
  const int hl = i % 3;
  const int j = i / 3;                  // 0..39
  const int bh = xcd * 3 + hl;
  int g, c;
  if (j < 16)      { g = 15 - (j >> 2); c = j & 3; }
  else if (j < 28) { const int u = j - 16; g = 11 - u / 3; c = u % 3; }
  else if (j < 36) { const int u = j - 28; g = 7 - (u >> 1); c = u & 1; }
  else             { g = 3 - (j - 36); c = 0; }
  const int qb = 4 * g + w;
  int cb;
  if (qb < 16)      cb = qb;
  else if (qb < 32) cb = 16 + 2 * (qb - 16);
  else if (qb < 48) cb = 48 + 3 * (qb - 32);
  else              cb = 96 + 4 * (qb - 48);
  const int pidx = bh * 160 + cb + c;

  const int b = bh / HH;
  const int hd = bh - b * HH;
  const int q0 = qb * 32;
  const int nt = qb / 2 + 1;
  const int t0 = c * 8;
  const int t1 = (t0 + 8 < nt) ? t0 + 8 : nt;

  const unsigned short* Qh = Q + (size_t)bh * BH_STRIDE;
  const unsigned short* Kh = Kb + (size_t)bh * BH_STRIDE;
  const unsigned short* Vh = Vt + (size_t)bh * BH_STRIDE;
  const unsigned int* mbp = mbits + b * 64;

  bf16x8 qf[4];
  {
    const unsigned short* qp = Qh + (q0 >> 5) * 2048 + lo;
#pragma unroll
    for (int dg = 0; dg < 4; ++dg)
      qf[dg] = *reinterpret_cast<const bf16x8*>(&qp[dg * 512]);
  }

  f32x16 o0 = {}, o1 = {};
  float lrow = 0.f;

  bf16x8 kfA[2][4], kfB[2][4];
  uint2 mbA, mbB;
  loadk(kfA, Kh, t0 * 64, lo);
  mbA = *reinterpret_cast<const uint2*>(&mbp[t0 * 2]);

  int t = t0;
  while (true) {
    if (t + 1 < t1) {
      loadk(kfB, Kh, (t + 1) * 64, lo);
      mbB = *reinterpret_cast<const uint2*>(&mbp[(t + 1) * 2]);
    }
    attn_tile(t * 64, kfA, mbA, qf, Vh, q0, l31, h, lo, o0, o1, lrow);
    ++t; if (t >= t1) break;
    if (t + 1 < t1) {
      loadk(kfA, Kh, (t + 1) * 64, lo);
      mbA = *reinterpret_cast<const uint2*>(&mbp[(t + 1) * 2]);
    }
    attn_tile(t * 64, kfB, mbB, qf, Vh, q0, l31, h, lo, o0, o1, lrow);
    ++t; if (t >= t1) break;
  }

  if (t0 == 0 && t1 == nt) {
    // solo chunk: normalize and write AO directly
    const float rl = 1.0f / lrow;
#pragma unroll
    for (int r = 0; r < 16; ++r) {
      const int crow = (r & 3) + 8 * (r >> 2) + 4 * h;
      const float rb = __shfl(rl, crow);
      const size_t base = (size_t)(b * TT + q0 + crow) * CC + hd * DD;
      AO[base + l31] = f2bf(o0[r] * rb);
      AO[base + 32 + l31] = f2bf(o1[r] * rb);
    }
  } else {
    // bf16 partials (halves partial traffic; one extra 2^-9-rel rounding)
    unsigned short* po = pO + (size_t)pidx * 2048;
#pragma unroll
    for (int r = 0; r < 16; ++r) {
      const int crow = (r & 3) + 8 * (r >> 2) + 4 * h;
      po[crow * 64 + l31] = f2bf(o0[r]);
      po[crow * 64 + 32 + l31] = f2bf(o1[r]);
    }
    if (lane < 32) {
      pL[pidx * 32 + lane] = lrow;
    }
  }
}

// ---------- phase 2: merge chunk partials for qb>=16 (plain sums, fixed-m) ----------
__global__ __launch_bounds__(256) void k_merge(
    const unsigned short* __restrict__ pO, const float* __restrict__ pL,
    unsigned short* __restrict__ AO) {
  const int qb = 16 + blockIdx.x, bh = blockIdx.y;
  const int b = bh / HH, hd = bh - b * HH;
  const int nt = qb / 2 + 1;
  const int nch = (nt + 7) >> 3;
  int cb;
  if (qb < 32)      cb = 16 + 2 * (qb - 16);
  else if (qb < 48) cb = 48 + 3 * (qb - 32);
  else              cb = 96 + 4 * (qb - 48);
  const int p0 = bh * 160 + cb;

  const int q = threadIdx.x >> 3;
  const int d0 = (threadIdx.x & 7) * 8;

  float lst = 0.f;
#pragma unroll
  for (int c = 0; c < 4; ++c)
    if (c < nch) lst += pL[(p0 + c) * 32 + q];
  const float inv = 1.0f / lst;

  float acc[8] = {};
#pragma unroll
  for (int c = 0; c < 4; ++c) {
    if (c < nch) {
      const unsigned short* po = pO + ((size_t)(p0 + c) * 32 + q) * 64 + d0;
      union { uint4 v; unsigned short u[8]; } rd;
      rd.v = *reinterpret_cast<const uint4*>(po);
#pragma unroll
      for (int jj = 0; jj < 8; ++jj) acc[jj] += bf2f(rd.u[jj]);
    }
  }
  union { unsigned short u[8]; uint4 v; } ov;
#pragma unroll
  for (int jj = 0; jj < 8; ++jj) ov.u[jj] = f2bf(acc[jj] * inv);
  *reinterpret_cast<uint4*>(&AO[(size_t)(b * TT + qb * 32 + q) * CC + hd * DD + d0]) = ov.v;
}

extern "C" void kernel_launch(void* const* d_in, const int* in_sizes, int n_in,
                              void* d_out, int out_size, void* d_ws, size_t ws_size,
                              hipStream_t stream) {
  const float* x   = (const float*)d_in[0];
  const int* mask  = (const int*)d_in[1];
  const float* Wa  = (const float*)d_in[2];
  const float* ba  = (const float*)d_in[3];
  const float* Wp  = (const float*)d_in[4];
  const float* bp  = (const float*)d_in[5];
  float* out = (float*)d_out;

  char* ws = (char*)d_ws;
  unsigned short* Xb  = (unsigned short*)(ws);                 // [4096][768]
  unsigned short* WaT = (unsigned short*)(ws + 6291456);       // [2304][768]
  unsigned short* WpT = (unsigned short*)(ws + 9830400);       // [768][768]
  unsigned short* Qb  = (unsigned short*)(ws + 11010048);      // frag layout
  unsigned short* Kb  = (unsigned short*)(ws + 17301504);      // frag layout
  unsigned short* Vt  = (unsigned short*)(ws + 23592960);      // frag layout
  unsigned short* AO  = (unsigned short*)(ws + 29884416);      // [4096][768]
  unsigned int*   Mb  = (unsigned int*)(ws + 36175872);        // [2][64] bitmask
  float*          pL  = (float*)(ws + 36667904);               // [3840][32] f32
  unsigned short* pO  = (unsigned short*)(ws + 37159424);      // [3840][32][64] bf16

  k_prep<<<dim3(PREP_CVT + PREP_TR1 + PREP_TR2 + 1), dim3(256), 0, stream>>>(
      x, Xb, Wa, WaT, Wp, WpT, mask, Mb);

  k_gemm<1, 128><<<dim3(MM / 128, N1 / 128), dim3(256), 0, stream>>>(
      Xb, WaT, ba, nullptr, N1, CC, Qb, Kb, Vt);

  k_attn<<<dim3(960), dim3(256), 0, stream>>>(Qb, Kb, Vt, Mb, pO, pL, AO);
  k_merge<<<dim3(48, BB * HH), dim3(256), 0, stream>>>(pO, pL, AO);

  k_gemm<0, 64><<<dim3(MM / 128, CC / 64), dim3(256), 0, stream>>>(
      AO, WpT, bp, out, CC, CC, nullptr, nullptr, nullptr);
}